// Round 6
// baseline (811.489 us; speedup 1.0000x reference)
//
#include <hip/hip_runtime.h>

#define NUM_USERS 100000
#define NUM_ITEMS 50000
#define N_NODES   150000   // NUM_USERS + NUM_ITEMS
#define EMBED_DIM 64
#define NUM_EDGES 4000000

#define N_USER4  (NUM_USERS * EMBED_DIM / 4)   // 1,600,000
#define N_TOT4   (N_NODES  * EMBED_DIM / 4)    // 2,400,000

#define SCAN_BLK  256
#define NBLK_SCAN ((N_NODES + SCAN_BLK - 1) / SCAN_BLK)   // 586

// bucket sort parameters: 74 buckets x 2048 rows
#define BROWS_SHIFT 11
#define BROWS       (1 << BROWS_SHIFT)                    // 2048
#define NB          ((N_NODES + BROWS - 1) / BROWS)       // 74
#define BIN_TILE    2048                                  // edges per tile

// bf16 helpers: store with round-to-nearest-even, load with shift (exact)
__device__ __forceinline__ unsigned short f2bf(float f) {
    unsigned int u = __float_as_uint(f);
    u = (u + 0x7fffu + ((u >> 16) & 1u)) >> 16;
    return (unsigned short)u;
}
__device__ __forceinline__ float bf2f(unsigned short b) {
    return __uint_as_float((unsigned int)b << 16);
}

// ---------------------------------------------------------------------------
// init: cur(bf16) = emb; out(fp32) = emb
// ---------------------------------------------------------------------------
__global__ void init_kernel(const float4* __restrict__ ue,
                            const float4* __restrict__ ie,
                            ushort4* __restrict__ cur_bf,
                            float4*  __restrict__ out) {
    int i = blockIdx.x * blockDim.x + threadIdx.x;
    if (i >= N_TOT4) return;
    float4 v = (i < N_USER4) ? ue[i] : ie[i - N_USER4];
    out[i] = v;
    ushort4 b;
    b.x = f2bf(v.x); b.y = f2bf(v.y); b.z = f2bf(v.z); b.w = f2bf(v.w);
    cur_bf[i] = b;
}

__global__ void zero_counts(int* __restrict__ c) {
    int i = blockIdx.x * blockDim.x + threadIdx.x;
    if (i < N_NODES) c[i] = 0;
}

// histogram of row indices
__global__ void hist_kernel(const int* __restrict__ row, int* __restrict__ counts) {
    int e = blockIdx.x * blockDim.x + threadIdx.x;
    if (e >= NUM_EDGES) return;
    atomicAdd(&counts[row[e]], 1);
}

// per-block exclusive scan of counts -> partial (into row_ptr), block totals
__global__ void scanA(const int* __restrict__ counts,
                      int* __restrict__ partial,
                      int* __restrict__ blockSums) {
    __shared__ int lds[SCAN_BLK];
    int tid = threadIdx.x;
    int i = blockIdx.x * SCAN_BLK + tid;
    int v = (i < N_NODES) ? counts[i] : 0;
    lds[tid] = v;
    __syncthreads();
    for (int off = 1; off < SCAN_BLK; off <<= 1) {
        int t = (tid >= off) ? lds[tid - off] : 0;
        __syncthreads();
        lds[tid] += t;
        __syncthreads();
    }
    int incl = lds[tid];
    if (i < N_NODES) partial[i] = incl - v;
    if (tid == SCAN_BLK - 1) blockSums[blockIdx.x] = incl;
}

// single-block exclusive scan of the 586 block totals
__global__ void scanB(int* __restrict__ blockSums) {
    __shared__ int lds[1024];
    int tid = threadIdx.x;
    int v = (tid < NBLK_SCAN) ? blockSums[tid] : 0;
    lds[tid] = v;
    __syncthreads();
    for (int off = 1; off < 1024; off <<= 1) {
        int t = (tid >= off) ? lds[tid - off] : 0;
        __syncthreads();
        lds[tid] += t;
        __syncthreads();
    }
    if (tid < NBLK_SCAN) blockSums[tid] = lds[tid] - v;
}

// finalize row_ptr = partial + blockOff; cursor = row_ptr; row_ptr[N]=E
__global__ void scanC(int* __restrict__ row_ptr,
                      const int* __restrict__ blockSums,
                      int* __restrict__ cursor) {
    int i = blockIdx.x * SCAN_BLK + threadIdx.x;
    if (i < N_NODES) {
        int rp = row_ptr[i] + blockSums[blockIdx.x];
        row_ptr[i] = rp;
        cursor[i]  = rp;
    }
    if (i == 0) row_ptr[N_NODES] = NUM_EDGES;
}

// bucket allocation cursors: bcur[b] = row_ptr[first row of bucket b]
__global__ void init_bcur(const int* __restrict__ row_ptr, int* __restrict__ bcur) {
    int b = threadIdx.x;
    if (b <= NB) {
        int r = b << BROWS_SHIFT;
        if (r > N_NODES) r = N_NODES;
        bcur[b] = row_ptr[r];
    }
}

// ---------------------------------------------------------------------------
// Pass 1: tile-reserved binning. Per 2048-edge tile: LDS histogram over 74
// buckets -> one global atomicAdd per bucket reserves a contiguous run in
// tmp -> direct writes. Bucket runs are sequential => line-merged writes
// (round-5 evidence: single-pass random scatter wrote 233 MB for 32 MB).
// tmp entry packs (row_local<<18 | col, val): col<2^18, row_local<2^11.
// ---------------------------------------------------------------------------
__global__ void bin_kernel(const int*   __restrict__ row,
                           const int*   __restrict__ col,
                           const float* __restrict__ val,
                           int*  __restrict__ bcur,
                           int2* __restrict__ tmp) {
    __shared__ int h[NB];
    __shared__ int base_[NB];
    int tid  = threadIdx.x;
    int tile = blockIdx.x;
    int e0   = tile * BIN_TILE;

    if (tid < NB) h[tid] = 0;
    __syncthreads();

    // count phase
    #pragma unroll
    for (int k = 0; k < BIN_TILE / 256; ++k) {
        int e = e0 + tid + k * 256;
        if (e < NUM_EDGES) atomicAdd(&h[row[e] >> BROWS_SHIFT], 1);
    }
    __syncthreads();

    // reserve phase
    if (tid < NB) {
        int c = h[tid];
        base_[tid] = c ? atomicAdd(&bcur[tid], c) : 0;
        h[tid] = 0;
    }
    __syncthreads();

    // write phase
    #pragma unroll
    for (int k = 0; k < BIN_TILE / 256; ++k) {
        int e = e0 + tid + k * 256;
        if (e < NUM_EDGES) {
            int r = row[e];
            int b = r >> BROWS_SHIFT;
            int slot = atomicAdd(&h[b], 1);
            int rl = r & (BROWS - 1);
            tmp[base_[b] + slot] = make_int2((rl << 18) | col[e],
                                             __float_as_int(val[e]));
        }
    }
}

// ---------------------------------------------------------------------------
// Pass 2: per-bucket scatter to final CSR position. Bucket b is processed
// only by blocks with blockIdx&7 == b&7 (XCD round-robin heuristic), so its
// 512 KB destination window stays in one XCD's L2 and partial lines merge.
// ---------------------------------------------------------------------------
__global__ void unbin_kernel(const int*  __restrict__ row_ptr,
                             const int2* __restrict__ tmp,
                             int*  __restrict__ cursor,
                             int2* __restrict__ packed) {
    int cls   = blockIdx.x & 7;
    int slice = blockIdx.x >> 3;
    int S     = gridDim.x >> 3;
    int tid   = threadIdx.x;

    for (int b = cls; b < NB; b += 8) {
        int rlo = b << BROWS_SHIFT;
        int rhi = rlo + BROWS; if (rhi > N_NODES) rhi = N_NODES;
        int lo = row_ptr[rlo];
        int hi = row_ptr[rhi];
        for (int i = lo + slice * 256 + tid; i < hi; i += S * 256) {
            int2 p = tmp[i];
            int rl = ((unsigned)p.x) >> 18;
            int c  = p.x & 0x3FFFF;
            int r  = rlo + rl;
            int pos = atomicAdd(&cursor[r], 1);
            packed[pos] = make_int2(c, p.y);
        }
    }
}

// ---------------------------------------------------------------------------
// SpMM gather, bf16 propagation buffers: one wave per row, lane = embed dim.
// MODE 0: y_bf = bf16(acc), out += acc      (layers 1,2)
// MODE 1: out = (out + acc) * 0.25          (layer 3; y not written)
// ---------------------------------------------------------------------------
template <int MODE>
__global__ void spmm_kernel(const int*  __restrict__ row_ptr,
                            const int2* __restrict__ packed,
                            const unsigned short* __restrict__ x,
                            unsigned short*       __restrict__ y,
                            float*                __restrict__ out) {
    int gid  = blockIdx.x * blockDim.x + threadIdx.x;
    int wid  = gid >> 6;           // row
    int lane = gid & 63;           // embed dim
    if (wid >= N_NODES) return;
    int s = row_ptr[wid];
    int e = row_ptr[wid + 1];

    float acc0 = 0.f, acc1 = 0.f, acc2 = 0.f, acc3 = 0.f;
    float acc4 = 0.f, acc5 = 0.f, acc6 = 0.f, acc7 = 0.f;

    for (int base = s; base < e; base += 64) {
        int idx = base + lane;
        int2 pk = make_int2(0, 0);
        if (idx < e) pk = packed[idx];          // one coalesced 512B txn / 64 edges
        int m = e - base; if (m > 64) m = 64;

        int j = 0;
        for (; j + 8 <= m; j += 8) {
            int c0 = __builtin_amdgcn_readlane(pk.x, j + 0);
            int c1 = __builtin_amdgcn_readlane(pk.x, j + 1);
            int c2 = __builtin_amdgcn_readlane(pk.x, j + 2);
            int c3 = __builtin_amdgcn_readlane(pk.x, j + 3);
            int c4 = __builtin_amdgcn_readlane(pk.x, j + 4);
            int c5 = __builtin_amdgcn_readlane(pk.x, j + 5);
            int c6 = __builtin_amdgcn_readlane(pk.x, j + 6);
            int c7 = __builtin_amdgcn_readlane(pk.x, j + 7);
            float x0 = bf2f(x[((long)c0 << 6) + lane]);
            float x1 = bf2f(x[((long)c1 << 6) + lane]);
            float x2 = bf2f(x[((long)c2 << 6) + lane]);
            float x3 = bf2f(x[((long)c3 << 6) + lane]);
            float x4 = bf2f(x[((long)c4 << 6) + lane]);
            float x5 = bf2f(x[((long)c5 << 6) + lane]);
            float x6 = bf2f(x[((long)c6 << 6) + lane]);
            float x7 = bf2f(x[((long)c7 << 6) + lane]);
            float v0 = __int_as_float(__builtin_amdgcn_readlane(pk.y, j + 0));
            float v1 = __int_as_float(__builtin_amdgcn_readlane(pk.y, j + 1));
            float v2 = __int_as_float(__builtin_amdgcn_readlane(pk.y, j + 2));
            float v3 = __int_as_float(__builtin_amdgcn_readlane(pk.y, j + 3));
            float v4 = __int_as_float(__builtin_amdgcn_readlane(pk.y, j + 4));
            float v5 = __int_as_float(__builtin_amdgcn_readlane(pk.y, j + 5));
            float v6 = __int_as_float(__builtin_amdgcn_readlane(pk.y, j + 6));
            float v7 = __int_as_float(__builtin_amdgcn_readlane(pk.y, j + 7));
            acc0 = fmaf(v0, x0, acc0);
            acc1 = fmaf(v1, x1, acc1);
            acc2 = fmaf(v2, x2, acc2);
            acc3 = fmaf(v3, x3, acc3);
            acc4 = fmaf(v4, x4, acc4);
            acc5 = fmaf(v5, x5, acc5);
            acc6 = fmaf(v6, x6, acc6);
            acc7 = fmaf(v7, x7, acc7);
        }
        for (; j < m; ++j) {
            int   c = __builtin_amdgcn_readlane(pk.x, j);
            float v = __int_as_float(__builtin_amdgcn_readlane(pk.y, j));
            acc0 = fmaf(v, bf2f(x[((long)c << 6) + lane]), acc0);
        }
    }
    float acc = ((acc0 + acc1) + (acc2 + acc3)) + ((acc4 + acc5) + (acc6 + acc7));

    long o = ((long)wid << 6) + lane;
    if (MODE == 0) {
        y[o] = f2bf(acc);
        out[o] += acc;
    } else {
        out[o] = (out[o] + acc) * 0.25f;
    }
}

// ------------------- fallback (round-1 atomic path, fp32) -------------------
__global__ void init_fp32_kernel(const float4* __restrict__ ue,
                                 const float4* __restrict__ ie,
                                 float4* __restrict__ cur,
                                 float4* __restrict__ out) {
    int i = blockIdx.x * blockDim.x + threadIdx.x;
    if (i >= N_TOT4) return;
    float4 v = (i < N_USER4) ? ue[i] : ie[i - N_USER4];
    cur[i] = v;
    out[i] = v;
}

__global__ void edge_kernel(const int*   __restrict__ row,
                            const int*   __restrict__ col,
                            const float* __restrict__ val,
                            const float* __restrict__ x,
                            float*       __restrict__ y) {
    long gid = (long)blockIdx.x * blockDim.x + threadIdx.x;
    int e = (int)(gid >> 4);
    if (e >= NUM_EDGES) return;
    int d = ((int)gid & 15) * 4;
    int   r = row[e];
    int   c = col[e];
    float v = val[e];
    const float4 xv = *(const float4*)(x + (long)c * EMBED_DIM + d);
    float* yp = y + (long)r * EMBED_DIM + d;
    atomicAdd(yp + 0, v * xv.x);
    atomicAdd(yp + 1, v * xv.y);
    atomicAdd(yp + 2, v * xv.z);
    atomicAdd(yp + 3, v * xv.w);
}

__global__ void update_kernel(float4* __restrict__ out,
                              const float4* __restrict__ nxt) {
    int i = blockIdx.x * blockDim.x + threadIdx.x;
    if (i >= N_TOT4) return;
    float4 o = out[i], n = nxt[i];
    o.x += n.x; o.y += n.y; o.z += n.z; o.w += n.w;
    out[i] = o;
}

__global__ void final_kernel(float4* __restrict__ out,
                             const float4* __restrict__ nxt) {
    int i = blockIdx.x * blockDim.x + threadIdx.x;
    if (i >= N_TOT4) return;
    float4 o = out[i], n = nxt[i];
    out[i] = make_float4((o.x + n.x) * 0.25f, (o.y + n.y) * 0.25f,
                         (o.z + n.z) * 0.25f, (o.w + n.w) * 0.25f);
}

__global__ void zero_buf_kernel(float4* __restrict__ b) {
    int i = blockIdx.x * blockDim.x + threadIdx.x;
    if (i < N_TOT4) b[i] = make_float4(0.f, 0.f, 0.f, 0.f);
}

extern "C" void kernel_launch(void* const* d_in, const int* in_sizes, int n_in,
                              void* d_out, int out_size, void* d_ws, size_t ws_size,
                              hipStream_t stream) {
    const float* user_emb  = (const float*)d_in[0];
    const float* item_emb  = (const float*)d_in[1];
    const float* edge_vals = (const float*)d_in[2];
    const int*   edge_row  = (const int*)  d_in[3];
    const int*   edge_col  = (const int*)  d_in[4];
    float* out = (float*)d_out;

    const int blk = 256;
    const int grid_nodes = (N_TOT4 + blk - 1) / blk;          // 9375
    const int grid_edges = (NUM_EDGES + blk - 1) / blk;       // 15625
    const int grid_spmm  = (N_NODES * 64 + blk - 1) / blk;    // 37500
    const int grid_bin   = (NUM_EDGES + BIN_TILE - 1) / BIN_TILE;  // 1954
    const int grid_unbin = 2048;                              // 8 classes x 256 slices

    const size_t BF     = (size_t)N_NODES * EMBED_DIM * sizeof(unsigned short); // 19.2 MB
    const size_t PACKED = (size_t)NUM_EDGES * sizeof(int2);                     // 32 MB
    const size_t RP     = 600064;                             // (N_NODES+1)*4 padded
    const size_t need   = 2 * BF + 2 * PACKED + 2 * RP + 8192;  // ~103.7 MB

    if (ws_size >= need) {
        unsigned short* bfA = (unsigned short*)d_ws;
        unsigned short* bfB = (unsigned short*)((char*)d_ws + BF);
        int2* packed   = (int2*)((char*)d_ws + 2 * BF);
        int2* tmp      = (int2*)((char*)d_ws + 2 * BF + PACKED);
        int*  row_ptr  = (int*) ((char*)d_ws + 2 * BF + 2 * PACKED);
        int*  cursor   = (int*) ((char*)d_ws + 2 * BF + 2 * PACKED + RP);
        int*  blockSum = (int*) ((char*)d_ws + 2 * BF + 2 * PACKED + 2 * RP);
        int*  bcur     = (int*) ((char*)d_ws + 2 * BF + 2 * PACKED + 2 * RP + 4096);

        init_kernel<<<grid_nodes, blk, 0, stream>>>(
            (const float4*)user_emb, (const float4*)item_emb,
            (ushort4*)bfA, (float4*)out);

        // --- build CSR: histogram + scan ---
        zero_counts<<<NBLK_SCAN, SCAN_BLK, 0, stream>>>(cursor);
        hist_kernel<<<grid_edges, blk, 0, stream>>>(edge_row, cursor);
        scanA<<<NBLK_SCAN, SCAN_BLK, 0, stream>>>(cursor, row_ptr, blockSum);
        scanB<<<1, 1024, 0, stream>>>(blockSum);
        scanC<<<NBLK_SCAN, SCAN_BLK, 0, stream>>>(row_ptr, blockSum, cursor);
        init_bcur<<<1, 128, 0, stream>>>(row_ptr, bcur);

        // --- two-pass binned permutation ---
        bin_kernel<<<grid_bin, blk, 0, stream>>>(edge_row, edge_col, edge_vals,
                                                 bcur, tmp);
        unbin_kernel<<<grid_unbin, blk, 0, stream>>>(row_ptr, tmp, cursor, packed);

        // --- 3 propagation layers, bf16 gather buffers, fused epilogues ---
        spmm_kernel<0><<<grid_spmm, blk, 0, stream>>>(row_ptr, packed, bfA, bfB, out);
        spmm_kernel<0><<<grid_spmm, blk, 0, stream>>>(row_ptr, packed, bfB, bfA, out);
        spmm_kernel<1><<<grid_spmm, blk, 0, stream>>>(row_ptr, packed, bfA, bfB, out);
    } else {
        // fallback: round-1 atomic scatter path (fp32, needs 76.8 MB)
        const size_t BUF = (size_t)N_NODES * EMBED_DIM * sizeof(float);
        float* bufA = (float*)d_ws;
        float* bufB = (float*)((char*)d_ws + BUF);
        const long edge_threads = (long)NUM_EDGES * 16;
        const int grid_edges16 = (int)((edge_threads + blk - 1) / blk);

        init_fp32_kernel<<<grid_nodes, blk, 0, stream>>>(
            (const float4*)user_emb, (const float4*)item_emb,
            (float4*)bufA, (float4*)out);
        zero_buf_kernel<<<grid_nodes, blk, 0, stream>>>((float4*)bufB);

        edge_kernel<<<grid_edges16, blk, 0, stream>>>(edge_row, edge_col, edge_vals, bufA, bufB);
        update_kernel<<<grid_nodes, blk, 0, stream>>>((float4*)out, (const float4*)bufB);
        zero_buf_kernel<<<grid_nodes, blk, 0, stream>>>((float4*)bufA);

        edge_kernel<<<grid_edges16, blk, 0, stream>>>(edge_row, edge_col, edge_vals, bufB, bufA);
        update_kernel<<<grid_nodes, blk, 0, stream>>>((float4*)out, (const float4*)bufA);
        zero_buf_kernel<<<grid_nodes, blk, 0, stream>>>((float4*)bufB);

        edge_kernel<<<grid_edges16, blk, 0, stream>>>(edge_row, edge_col, edge_vals, bufA, bufB);
        final_kernel<<<grid_nodes, blk, 0, stream>>>((float4*)out, (const float4*)bufB);
    }
}

// Round 7
// 601.070 us; speedup vs baseline: 1.3501x; 1.3501x over previous
//
#include <hip/hip_runtime.h>

#define NUM_USERS 100000
#define NUM_ITEMS 50000
#define N_NODES   150000   // NUM_USERS + NUM_ITEMS
#define EMBED_DIM 64
#define NUM_EDGES 4000000

#define N_USER4  (NUM_USERS * EMBED_DIM / 4)   // 1,600,000
#define N_TOT4   (N_NODES  * EMBED_DIM / 4)    // 2,400,000

// bucket sort parameters: 74 buckets x 2048 rows
#define BROWS_SHIFT 11
#define BROWS       (1 << BROWS_SHIFT)                    // 2048
#define NB          ((N_NODES + BROWS - 1) / BROWS)       // 74
#define BIN_TILE    2048                                  // edges per tile
#define NTILES      ((NUM_EDGES + BIN_TILE - 1) / BIN_TILE)  // 1954

// bf16 helpers: store with round-to-nearest-even, load with shift (exact)
__device__ __forceinline__ unsigned short f2bf(float f) {
    unsigned int u = __float_as_uint(f);
    u = (u + 0x7fffu + ((u >> 16) & 1u)) >> 16;
    return (unsigned short)u;
}
__device__ __forceinline__ float bf2f(unsigned short b) {
    return __uint_as_float((unsigned int)b << 16);
}

// ---------------------------------------------------------------------------
// init: cur(bf16) = emb; out(fp32) = emb
// ---------------------------------------------------------------------------
__global__ void init_kernel(const float4* __restrict__ ue,
                            const float4* __restrict__ ie,
                            ushort4* __restrict__ cur_bf,
                            float4*  __restrict__ out) {
    int i = blockIdx.x * blockDim.x + threadIdx.x;
    if (i >= N_TOT4) return;
    float4 v = (i < N_USER4) ? ue[i] : ie[i - N_USER4];
    out[i] = v;
    ushort4 b;
    b.x = f2bf(v.x); b.y = f2bf(v.y); b.z = f2bf(v.z); b.w = f2bf(v.w);
    cur_bf[i] = b;
}

__global__ void zero_meta(int* __restrict__ m) {
    if (threadIdx.x < 128) m[threadIdx.x] = 0;
}

// ---------------------------------------------------------------------------
// Pass 0: bucket totals. LDS hist over 74 buckets per 2048-edge tile, then
// one global atomicAdd per (tile,bucket) = 145K atomics total (round-6
// evidence: 4M per-edge atomics on a 600KB array wrote 124.8 MB to HBM).
// ---------------------------------------------------------------------------
__global__ void bin_count(const int* __restrict__ row, int* __restrict__ btot) {
    __shared__ int h[NB];
    int tid = threadIdx.x;
    int e0  = blockIdx.x * BIN_TILE;
    if (tid < NB) h[tid] = 0;
    __syncthreads();
    #pragma unroll
    for (int k = 0; k < BIN_TILE / 256; ++k) {
        int e = e0 + tid + k * 256;
        if (e < NUM_EDGES) atomicAdd(&h[row[e] >> BROWS_SHIFT], 1);
    }
    __syncthreads();
    if (tid < NB && h[tid] > 0) atomicAdd(&btot[tid], h[tid]);
}

// single-thread scan of 74 bucket totals -> bucket_off, bcur
__global__ void bucket_scan(const int* __restrict__ btot,
                            int* __restrict__ boff,
                            int* __restrict__ bcur) {
    if (threadIdx.x == 0) {
        int s = 0;
        for (int b = 0; b < NB; ++b) { boff[b] = s; bcur[b] = s; s += btot[b]; }
        boff[NB] = s;   // == NUM_EDGES
    }
}

// ---------------------------------------------------------------------------
// Pass 1: LDS-staged bucket sort per tile. Rank via LDS atomics, stage the
// 2048 entries bucket-ordered in LDS, then write each bucket's run to tmp
// with consecutive threads -> coalesced stores (round-6 bin_kernel wrote 8B
// scattered stores, one transaction per edge).
// tmp entry packs (row_local<<18 | col, val): col<2^18, row_local<2^11.
// ---------------------------------------------------------------------------
__global__ void bin_write(const int*   __restrict__ row,
                          const int*   __restrict__ col,
                          const float* __restrict__ val,
                          int*  __restrict__ bcur,
                          int2* __restrict__ tmp) {
    __shared__ int2 sbuf[BIN_TILE];              // 16 KB
    __shared__ unsigned char sbk[BIN_TILE];      // 2 KB
    __shared__ int h[NB], lbase[NB], gbase[NB];
    int tid = threadIdx.x;
    int e0  = blockIdx.x * BIN_TILE;

    if (tid < NB) h[tid] = 0;
    __syncthreads();

    // rank phase: per-edge within-tile rank in its bucket
    int bk[BIN_TILE / 256], rk[BIN_TILE / 256], rl[BIN_TILE / 256];
    #pragma unroll
    for (int k = 0; k < BIN_TILE / 256; ++k) {
        int e = e0 + tid + k * 256;
        bk[k] = -1;
        if (e < NUM_EDGES) {
            int r = row[e];
            int b = r >> BROWS_SHIFT;
            bk[k] = b;
            rl[k] = r & (BROWS - 1);
            rk[k] = atomicAdd(&h[b], 1);
        }
    }
    __syncthreads();

    // scan + reserve
    if (tid == 0) {
        int s = 0;
        for (int b = 0; b < NB; ++b) { lbase[b] = s; s += h[b]; }
    }
    __syncthreads();
    if (tid < NB && h[tid] > 0) gbase[tid] = atomicAdd(&bcur[tid], h[tid]);
    __syncthreads();

    // place phase: stage bucket-ordered in LDS
    #pragma unroll
    for (int k = 0; k < BIN_TILE / 256; ++k) {
        int e = e0 + tid + k * 256;
        if (bk[k] >= 0) {
            int slot = lbase[bk[k]] + rk[k];
            sbuf[slot] = make_int2((rl[k] << 18) | col[e], __float_as_int(val[e]));
            sbk[slot]  = (unsigned char)bk[k];
        }
    }
    __syncthreads();

    // write phase: consecutive slots of one bucket -> consecutive global addrs
    int nt = NUM_EDGES - e0; if (nt > BIN_TILE) nt = BIN_TILE;
    for (int i = tid; i < nt; i += 256) {
        int b = sbk[i];
        tmp[gbase[b] + (i - lbase[b])] = sbuf[i];
    }
}

// ---------------------------------------------------------------------------
// Pass 2: per-bucket finalize. One 1024-thread block per bucket: 2048-bin
// LDS histogram + scan -> row_ptr segment; scatter to final packed position
// via LDS cursors. No global cursor atomics; destination window = bucket
// size (~430 KB) stays in the CU's XCD L2 so partial lines merge.
// ---------------------------------------------------------------------------
__global__ void finalize_bucket(const int2* __restrict__ tmp,
                                const int*  __restrict__ boff,
                                int*  __restrict__ row_ptr,
                                int2* __restrict__ packed) {
    __shared__ int cnt[BROWS];    // 8 KB: counts, then cursors
    __shared__ int ps[1024];      // 4 KB: scan partials
    int tid = threadIdx.x;
    int b   = blockIdx.x;
    int rlo = b << BROWS_SHIFT;
    int nrows = N_NODES - rlo; if (nrows > BROWS) nrows = BROWS;
    int lo = boff[b];
    int hi = boff[b + 1];

    cnt[2 * tid]     = 0;
    cnt[2 * tid + 1] = 0;
    __syncthreads();

    // histogram of row_local
    for (int i = lo + tid; i < hi; i += 1024)
        atomicAdd(&cnt[((unsigned)tmp[i].x) >> 18], 1);
    __syncthreads();

    // scan 2048 (2 elems/thread): thread-pair sum -> Hillis-Steele over 1024
    int a0 = cnt[2 * tid], a1 = cnt[2 * tid + 1];
    int ts = a0 + a1;
    ps[tid] = ts;
    __syncthreads();
    for (int off = 1; off < 1024; off <<= 1) {
        int t = (tid >= off) ? ps[tid - off] : 0;
        __syncthreads();
        ps[tid] += t;
        __syncthreads();
    }
    int excl = ps[tid] - ts;   // exclusive prefix of this thread's pair

    // cursors + row_ptr
    cnt[2 * tid]     = excl;
    cnt[2 * tid + 1] = excl + a0;
    if (2 * tid < nrows)     row_ptr[rlo + 2 * tid]     = lo + excl;
    if (2 * tid + 1 < nrows) row_ptr[rlo + 2 * tid + 1] = lo + excl + a0;
    if (b == NB - 1 && tid == 0) row_ptr[N_NODES] = NUM_EDGES;
    __syncthreads();

    // scatter to final position
    for (int i = lo + tid; i < hi; i += 1024) {
        int2 p = tmp[i];
        int r = ((unsigned)p.x) >> 18;
        int pos = lo + atomicAdd(&cnt[r], 1);
        packed[pos] = make_int2(p.x & 0x3FFFF, p.y);
    }
}

// ---------------------------------------------------------------------------
// SpMM gather, bf16 propagation buffers: one wave per row, lane = embed dim.
// MODE 0: y_bf = bf16(acc), out += acc      (layers 1,2)
// MODE 1: out = (out + acc) * 0.25          (layer 3; y not written)
// ---------------------------------------------------------------------------
template <int MODE>
__global__ void spmm_kernel(const int*  __restrict__ row_ptr,
                            const int2* __restrict__ packed,
                            const unsigned short* __restrict__ x,
                            unsigned short*       __restrict__ y,
                            float*                __restrict__ out) {
    int gid  = blockIdx.x * blockDim.x + threadIdx.x;
    int wid  = gid >> 6;           // row
    int lane = gid & 63;           // embed dim
    if (wid >= N_NODES) return;
    int s = row_ptr[wid];
    int e = row_ptr[wid + 1];

    float acc0 = 0.f, acc1 = 0.f, acc2 = 0.f, acc3 = 0.f;
    float acc4 = 0.f, acc5 = 0.f, acc6 = 0.f, acc7 = 0.f;

    for (int base = s; base < e; base += 64) {
        int idx = base + lane;
        int2 pk = make_int2(0, 0);
        if (idx < e) pk = packed[idx];          // one coalesced 512B txn / 64 edges
        int m = e - base; if (m > 64) m = 64;

        int j = 0;
        for (; j + 8 <= m; j += 8) {
            int c0 = __builtin_amdgcn_readlane(pk.x, j + 0);
            int c1 = __builtin_amdgcn_readlane(pk.x, j + 1);
            int c2 = __builtin_amdgcn_readlane(pk.x, j + 2);
            int c3 = __builtin_amdgcn_readlane(pk.x, j + 3);
            int c4 = __builtin_amdgcn_readlane(pk.x, j + 4);
            int c5 = __builtin_amdgcn_readlane(pk.x, j + 5);
            int c6 = __builtin_amdgcn_readlane(pk.x, j + 6);
            int c7 = __builtin_amdgcn_readlane(pk.x, j + 7);
            float x0 = bf2f(x[((long)c0 << 6) + lane]);
            float x1 = bf2f(x[((long)c1 << 6) + lane]);
            float x2 = bf2f(x[((long)c2 << 6) + lane]);
            float x3 = bf2f(x[((long)c3 << 6) + lane]);
            float x4 = bf2f(x[((long)c4 << 6) + lane]);
            float x5 = bf2f(x[((long)c5 << 6) + lane]);
            float x6 = bf2f(x[((long)c6 << 6) + lane]);
            float x7 = bf2f(x[((long)c7 << 6) + lane]);
            float v0 = __int_as_float(__builtin_amdgcn_readlane(pk.y, j + 0));
            float v1 = __int_as_float(__builtin_amdgcn_readlane(pk.y, j + 1));
            float v2 = __int_as_float(__builtin_amdgcn_readlane(pk.y, j + 2));
            float v3 = __int_as_float(__builtin_amdgcn_readlane(pk.y, j + 3));
            float v4 = __int_as_float(__builtin_amdgcn_readlane(pk.y, j + 4));
            float v5 = __int_as_float(__builtin_amdgcn_readlane(pk.y, j + 5));
            float v6 = __int_as_float(__builtin_amdgcn_readlane(pk.y, j + 6));
            float v7 = __int_as_float(__builtin_amdgcn_readlane(pk.y, j + 7));
            acc0 = fmaf(v0, x0, acc0);
            acc1 = fmaf(v1, x1, acc1);
            acc2 = fmaf(v2, x2, acc2);
            acc3 = fmaf(v3, x3, acc3);
            acc4 = fmaf(v4, x4, acc4);
            acc5 = fmaf(v5, x5, acc5);
            acc6 = fmaf(v6, x6, acc6);
            acc7 = fmaf(v7, x7, acc7);
        }
        for (; j < m; ++j) {
            int   c = __builtin_amdgcn_readlane(pk.x, j);
            float v = __int_as_float(__builtin_amdgcn_readlane(pk.y, j));
            acc0 = fmaf(v, bf2f(x[((long)c << 6) + lane]), acc0);
        }
    }
    float acc = ((acc0 + acc1) + (acc2 + acc3)) + ((acc4 + acc5) + (acc6 + acc7));

    long o = ((long)wid << 6) + lane;
    if (MODE == 0) {
        y[o] = f2bf(acc);
        out[o] += acc;
    } else {
        out[o] = (out[o] + acc) * 0.25f;
    }
}

// ------------------- fallback (round-1 atomic path, fp32) -------------------
__global__ void init_fp32_kernel(const float4* __restrict__ ue,
                                 const float4* __restrict__ ie,
                                 float4* __restrict__ cur,
                                 float4* __restrict__ out) {
    int i = blockIdx.x * blockDim.x + threadIdx.x;
    if (i >= N_TOT4) return;
    float4 v = (i < N_USER4) ? ue[i] : ie[i - N_USER4];
    cur[i] = v;
    out[i] = v;
}

__global__ void edge_kernel(const int*   __restrict__ row,
                            const int*   __restrict__ col,
                            const float* __restrict__ val,
                            const float* __restrict__ x,
                            float*       __restrict__ y) {
    long gid = (long)blockIdx.x * blockDim.x + threadIdx.x;
    int e = (int)(gid >> 4);
    if (e >= NUM_EDGES) return;
    int d = ((int)gid & 15) * 4;
    int   r = row[e];
    int   c = col[e];
    float v = val[e];
    const float4 xv = *(const float4*)(x + (long)c * EMBED_DIM + d);
    float* yp = y + (long)r * EMBED_DIM + d;
    atomicAdd(yp + 0, v * xv.x);
    atomicAdd(yp + 1, v * xv.y);
    atomicAdd(yp + 2, v * xv.z);
    atomicAdd(yp + 3, v * xv.w);
}

__global__ void update_kernel(float4* __restrict__ out,
                              const float4* __restrict__ nxt) {
    int i = blockIdx.x * blockDim.x + threadIdx.x;
    if (i >= N_TOT4) return;
    float4 o = out[i], n = nxt[i];
    o.x += n.x; o.y += n.y; o.z += n.z; o.w += n.w;
    out[i] = o;
}

__global__ void final_kernel(float4* __restrict__ out,
                             const float4* __restrict__ nxt) {
    int i = blockIdx.x * blockDim.x + threadIdx.x;
    if (i >= N_TOT4) return;
    float4 o = out[i], n = nxt[i];
    out[i] = make_float4((o.x + n.x) * 0.25f, (o.y + n.y) * 0.25f,
                         (o.z + n.z) * 0.25f, (o.w + n.w) * 0.25f);
}

__global__ void zero_buf_kernel(float4* __restrict__ b) {
    int i = blockIdx.x * blockDim.x + threadIdx.x;
    if (i < N_TOT4) b[i] = make_float4(0.f, 0.f, 0.f, 0.f);
}

extern "C" void kernel_launch(void* const* d_in, const int* in_sizes, int n_in,
                              void* d_out, int out_size, void* d_ws, size_t ws_size,
                              hipStream_t stream) {
    const float* user_emb  = (const float*)d_in[0];
    const float* item_emb  = (const float*)d_in[1];
    const float* edge_vals = (const float*)d_in[2];
    const int*   edge_row  = (const int*)  d_in[3];
    const int*   edge_col  = (const int*)  d_in[4];
    float* out = (float*)d_out;

    const int blk = 256;
    const int grid_nodes = (N_TOT4 + blk - 1) / blk;          // 9375
    const int grid_spmm  = (N_NODES * 64 + blk - 1) / blk;    // 37500

    const size_t BF     = (size_t)N_NODES * EMBED_DIM * sizeof(unsigned short); // 19.2 MB
    const size_t PACKED = (size_t)NUM_EDGES * sizeof(int2);                     // 32 MB
    const size_t RP     = 600064;                             // (N_NODES+1)*4 padded
    const size_t need   = 2 * BF + 2 * PACKED + RP + 4096;    // ~103.1 MB

    if (ws_size >= need) {
        unsigned short* bfA = (unsigned short*)d_ws;
        unsigned short* bfB = (unsigned short*)((char*)d_ws + BF);
        int2* packed  = (int2*)((char*)d_ws + 2 * BF);
        int2* tmp     = (int2*)((char*)d_ws + 2 * BF + PACKED);
        int*  row_ptr = (int*) ((char*)d_ws + 2 * BF + 2 * PACKED);
        int*  meta    = (int*) ((char*)d_ws + 2 * BF + 2 * PACKED + RP);
        int*  btot = meta;          // 128 ints
        int*  boff = meta + 128;    // 128 ints (NB+1 used)
        int*  bcur = meta + 256;    // 128 ints

        init_kernel<<<grid_nodes, blk, 0, stream>>>(
            (const float4*)user_emb, (const float4*)item_emb,
            (ushort4*)bfA, (float4*)out);

        // --- build CSR: bucket totals -> scan -> staged bin -> finalize ---
        zero_meta<<<1, 128, 0, stream>>>(btot);
        bin_count<<<NTILES, blk, 0, stream>>>(edge_row, btot);
        bucket_scan<<<1, 64, 0, stream>>>(btot, boff, bcur);
        bin_write<<<NTILES, blk, 0, stream>>>(edge_row, edge_col, edge_vals,
                                              bcur, tmp);
        finalize_bucket<<<NB, 1024, 0, stream>>>(tmp, boff, row_ptr, packed);

        // --- 3 propagation layers, bf16 gather buffers, fused epilogues ---
        spmm_kernel<0><<<grid_spmm, blk, 0, stream>>>(row_ptr, packed, bfA, bfB, out);
        spmm_kernel<0><<<grid_spmm, blk, 0, stream>>>(row_ptr, packed, bfB, bfA, out);
        spmm_kernel<1><<<grid_spmm, blk, 0, stream>>>(row_ptr, packed, bfA, bfB, out);
    } else {
        // fallback: round-1 atomic scatter path (fp32, needs 76.8 MB)
        const size_t BUF = (size_t)N_NODES * EMBED_DIM * sizeof(float);
        float* bufA = (float*)d_ws;
        float* bufB = (float*)((char*)d_ws + BUF);
        const long edge_threads = (long)NUM_EDGES * 16;
        const int grid_edges16 = (int)((edge_threads + blk - 1) / blk);

        init_fp32_kernel<<<grid_nodes, blk, 0, stream>>>(
            (const float4*)user_emb, (const float4*)item_emb,
            (float4*)bufA, (float4*)out);
        zero_buf_kernel<<<grid_nodes, blk, 0, stream>>>((float4*)bufB);

        edge_kernel<<<grid_edges16, blk, 0, stream>>>(edge_row, edge_col, edge_vals, bufA, bufB);
        update_kernel<<<grid_nodes, blk, 0, stream>>>((float4*)out, (const float4*)bufB);
        zero_buf_kernel<<<grid_nodes, blk, 0, stream>>>((float4*)bufA);

        edge_kernel<<<grid_edges16, blk, 0, stream>>>(edge_row, edge_col, edge_vals, bufB, bufA);
        update_kernel<<<grid_nodes, blk, 0, stream>>>((float4*)out, (const float4*)bufA);
        zero_buf_kernel<<<grid_nodes, blk, 0, stream>>>((float4*)bufB);

        edge_kernel<<<grid_edges16, blk, 0, stream>>>(edge_row, edge_col, edge_vals, bufA, bufB);
        final_kernel<<<grid_nodes, blk, 0, stream>>>((float4*)out, (const float4*)bufB);
    }
}

// Round 8
// 517.486 us; speedup vs baseline: 1.5681x; 1.1615x over previous
//
#include <hip/hip_runtime.h>

#define NUM_USERS 100000
#define NUM_ITEMS 50000
#define N_NODES   150000   // NUM_USERS + NUM_ITEMS
#define EMBED_DIM 64
#define NUM_EDGES 4000000

#define N_USER4  (NUM_USERS * EMBED_DIM / 4)   // 1,600,000
#define N_TOT4   (N_NODES  * EMBED_DIM / 4)    // 2,400,000

// bucket sort parameters: 586 buckets x 256 rows
#define BROWS_SHIFT 8
#define BROWS       (1 << BROWS_SHIFT)                    // 256
#define NB          ((N_NODES + BROWS - 1) / BROWS)       // 586
#define BIN_TILE    4096                                  // edges per tile
#define NTILES      ((NUM_EDGES + BIN_TILE - 1) / BIN_TILE)  // 977
#define CAP         8192   // tmp slots per bucket (mean 6826, sigma 83 -> +16s)

// bf16 helpers: store with round-to-nearest-even, load with shift (exact)
__device__ __forceinline__ unsigned short f2bf(float f) {
    unsigned int u = __float_as_uint(f);
    u = (u + 0x7fffu + ((u >> 16) & 1u)) >> 16;
    return (unsigned short)u;
}
__device__ __forceinline__ float bf2f(unsigned short b) {
    return __uint_as_float((unsigned int)b << 16);
}

// ---------------------------------------------------------------------------
// init: cur(bf16) = emb; out(fp32) = emb
// ---------------------------------------------------------------------------
__global__ void init_kernel(const float4* __restrict__ ue,
                            const float4* __restrict__ ie,
                            ushort4* __restrict__ cur_bf,
                            float4*  __restrict__ out) {
    int i = blockIdx.x * blockDim.x + threadIdx.x;
    if (i >= N_TOT4) return;
    float4 v = (i < N_USER4) ? ue[i] : ie[i - N_USER4];
    out[i] = v;
    ushort4 b;
    b.x = f2bf(v.x); b.y = f2bf(v.y); b.z = f2bf(v.z); b.w = f2bf(v.w);
    cur_bf[i] = b;
}

// ---------------------------------------------------------------------------
// Pass 0: per-tile bucket counts -> cnt[tile][bucket], coalesced stores.
// Zero global atomics (round-6/7 evidence: global atomics on small arrays
// are the dominant write-amplification disease).
// ---------------------------------------------------------------------------
__global__ void bin_count(const int* __restrict__ row, int* __restrict__ cnt) {
    __shared__ int h[NB];
    int tid = threadIdx.x;
    long e0 = (long)blockIdx.x * BIN_TILE;
    for (int i = tid; i < NB; i += 256) h[i] = 0;
    __syncthreads();
    #pragma unroll
    for (int k = 0; k < BIN_TILE / 256; ++k) {
        long e = e0 + tid + k * 256;
        if (e < NUM_EDGES) atomicAdd(&h[row[e] >> BROWS_SHIFT], 1);
    }
    __syncthreads();
    int* dst = cnt + (long)blockIdx.x * NB;
    for (int i = tid; i < NB; i += 256) dst[i] = h[i];
}

// ---------------------------------------------------------------------------
// Per-bucket column scan: cnt[t][b] -> exclusive prefix over tiles (in place),
// tot[b] = bucket total. One block per bucket, 4 tiles/thread chunked scan.
// ---------------------------------------------------------------------------
__global__ void col_scan(int* __restrict__ cnt, int* __restrict__ tot) {
    __shared__ int ps[256];
    int b = blockIdx.x, tid = threadIdx.x;
    int v[4]; int s = 0;
    #pragma unroll
    for (int j = 0; j < 4; ++j) {
        int t = tid * 4 + j;
        v[j] = (t < NTILES) ? cnt[(long)t * NB + b] : 0;
        s += v[j];
    }
    ps[tid] = s;
    __syncthreads();
    for (int off = 1; off < 256; off <<= 1) {
        int t = (tid >= off) ? ps[tid - off] : 0;
        __syncthreads();
        ps[tid] += t;
        __syncthreads();
    }
    int excl = ps[tid] - s;
    #pragma unroll
    for (int j = 0; j < 4; ++j) {
        int t = tid * 4 + j;
        if (t < NTILES) { cnt[(long)t * NB + b] = excl; excl += v[j]; }
    }
    if (tid == 255) tot[b] = ps[255];
}

// exclusive scan of 586 bucket totals -> boff (CSR bucket offsets)
__global__ void boff_scan(const int* __restrict__ tot, int* __restrict__ boff) {
    __shared__ int lds[1024];
    int tid = threadIdx.x;
    int v = (tid < NB) ? tot[tid] : 0;
    lds[tid] = v;
    __syncthreads();
    for (int off = 1; off < 1024; off <<= 1) {
        int t = (tid >= off) ? lds[tid - off] : 0;
        __syncthreads();
        lds[tid] += t;
        __syncthreads();
    }
    if (tid < NB) boff[tid] = lds[tid] - v;
    if (tid == 0) boff[NB] = NUM_EDGES;
}

// ---------------------------------------------------------------------------
// Pass 1: LDS-staged bucket sort per 4096-edge tile. Ranks via LDS atomics,
// bases read from the scanned cnt row (no global atomics), stage bucket-
// ordered in LDS, write runs coalesced into fixed-CAP bucket regions of tmp.
// tmp entry packs (rl<<18 | col, val): col<2^18, rl<2^8.
// pkreg packs (b<<20 | rl<<12 | rk): b<1024, rl<256, rk<4096.
// ---------------------------------------------------------------------------
__global__ void bin_write(const int*   __restrict__ row,
                          const int*   __restrict__ col,
                          const float* __restrict__ val,
                          const int*   __restrict__ cnt,   // scanned bases
                          int2* __restrict__ tmp) {
    __shared__ int2 sbuf[BIN_TILE];                 // 32 KB
    __shared__ unsigned short sbk[BIN_TILE];        // 8 KB
    __shared__ int h[NB];                           // counts, then gbase
    __shared__ int lbase[NB];
    __shared__ int ps[256];
    int tid = threadIdx.x;
    long e0 = (long)blockIdx.x * BIN_TILE;

    for (int i = tid; i < NB; i += 256) h[i] = 0;
    __syncthreads();

    // rank phase
    int pkreg[BIN_TILE / 256];
    #pragma unroll
    for (int k = 0; k < BIN_TILE / 256; ++k) {
        long e = e0 + tid + k * 256;
        pkreg[k] = -1;
        if (e < NUM_EDGES) {
            int r  = row[e];
            int b  = r >> BROWS_SHIFT;
            int rl = r & (BROWS - 1);
            int rk = atomicAdd(&h[b], 1);
            pkreg[k] = (b << 20) | (rl << 12) | rk;
        }
    }
    __syncthreads();

    // exclusive scan of h[NB] -> lbase (3 bins/thread chunked)
    int a[3]; int s = 0;
    #pragma unroll
    for (int j = 0; j < 3; ++j) {
        int i = tid * 3 + j;
        a[j] = (i < NB) ? h[i] : 0;
        s += a[j];
    }
    ps[tid] = s;
    __syncthreads();
    for (int off = 1; off < 256; off <<= 1) {
        int t = (tid >= off) ? ps[tid - off] : 0;
        __syncthreads();
        ps[tid] += t;
        __syncthreads();
    }
    int excl = ps[tid] - s;
    #pragma unroll
    for (int j = 0; j < 3; ++j) {
        int i = tid * 3 + j;
        if (i < NB) { lbase[i] = excl; excl += a[j]; }
    }
    __syncthreads();

    // overwrite h with per-tile global bases within each bucket
    for (int i = tid; i < NB; i += 256) h[i] = cnt[(long)blockIdx.x * NB + i];

    // place phase: stage bucket-ordered in LDS (col/val read once, here)
    #pragma unroll
    for (int k = 0; k < BIN_TILE / 256; ++k) {
        if (pkreg[k] >= 0) {
            long e = e0 + tid + k * 256;
            int b  = pkreg[k] >> 20;
            int rl = (pkreg[k] >> 12) & 255;
            int rk = pkreg[k] & 4095;
            int slot = lbase[b] + rk;
            sbuf[slot] = make_int2((rl << 18) | col[e], __float_as_int(val[e]));
            sbk[slot]  = (unsigned short)b;
        }
    }
    __syncthreads();

    // write phase: consecutive slots of a bucket -> consecutive global addrs
    long rem = NUM_EDGES - e0;
    int nt = (rem < BIN_TILE) ? (int)rem : BIN_TILE;
    for (int i = tid; i < nt; i += 256) {
        int b = sbk[i];
        tmp[(long)b * CAP + h[b] + (i - lbase[b])] = sbuf[i];
    }
}

// ---------------------------------------------------------------------------
// Pass 2: per-bucket finalize, full occupancy (586 blocks x 256 thr; round-7
// version ran 74 blocks = 29% of CUs). 256-bin LDS hist + scan -> row_ptr;
// scatter to final packed position via LDS cursors (54 KB window).
// ---------------------------------------------------------------------------
__global__ void finalize_bucket(const int2* __restrict__ tmp,
                                const int*  __restrict__ tot,
                                const int*  __restrict__ boff,
                                int*  __restrict__ row_ptr,
                                int2* __restrict__ packed) {
    __shared__ int cnt_[BROWS];
    __shared__ int ps[256];
    int tid = threadIdx.x;
    int b   = blockIdx.x;
    long lo_t = (long)b * CAP;
    int n    = tot[b];
    int base = boff[b];
    int rlo  = b << BROWS_SHIFT;

    cnt_[tid] = 0;
    __syncthreads();

    for (int i = tid; i < n; i += 256)
        atomicAdd(&cnt_[((unsigned)tmp[lo_t + i].x) >> 18], 1);
    __syncthreads();

    int v = cnt_[tid];
    ps[tid] = v;
    __syncthreads();
    for (int off = 1; off < 256; off <<= 1) {
        int t = (tid >= off) ? ps[tid - off] : 0;
        __syncthreads();
        ps[tid] += t;
        __syncthreads();
    }
    int excl = ps[tid] - v;

    int r = rlo + tid;
    if (r < N_NODES) row_ptr[r] = base + excl;
    if (b == NB - 1 && tid == 0) row_ptr[N_NODES] = NUM_EDGES;
    cnt_[tid] = base + excl;   // cursor
    __syncthreads();

    for (int i = tid; i < n; i += 256) {
        int2 p = tmp[lo_t + i];
        int rl = ((unsigned)p.x) >> 18;
        int pos = atomicAdd(&cnt_[rl], 1);
        packed[pos] = make_int2(p.x & 0x3FFFF, p.y);
    }
}

// ---------------------------------------------------------------------------
// SpMM gather, bf16 propagation buffers: one wave per row, lane = embed dim.
// MODE 0: y_bf = bf16(acc), out += acc      (layers 1,2)
// MODE 1: out = (out + acc) * 0.25          (layer 3; y not written)
// ---------------------------------------------------------------------------
template <int MODE>
__global__ void spmm_kernel(const int*  __restrict__ row_ptr,
                            const int2* __restrict__ packed,
                            const unsigned short* __restrict__ x,
                            unsigned short*       __restrict__ y,
                            float*                __restrict__ out) {
    int gid  = blockIdx.x * blockDim.x + threadIdx.x;
    int wid  = gid >> 6;           // row
    int lane = gid & 63;           // embed dim
    if (wid >= N_NODES) return;
    int s = row_ptr[wid];
    int e = row_ptr[wid + 1];

    float acc0 = 0.f, acc1 = 0.f, acc2 = 0.f, acc3 = 0.f;
    float acc4 = 0.f, acc5 = 0.f, acc6 = 0.f, acc7 = 0.f;

    for (int base = s; base < e; base += 64) {
        int idx = base + lane;
        int2 pk = make_int2(0, 0);
        if (idx < e) pk = packed[idx];          // one coalesced 512B txn / 64 edges
        int m = e - base; if (m > 64) m = 64;

        int j = 0;
        for (; j + 8 <= m; j += 8) {
            int c0 = __builtin_amdgcn_readlane(pk.x, j + 0);
            int c1 = __builtin_amdgcn_readlane(pk.x, j + 1);
            int c2 = __builtin_amdgcn_readlane(pk.x, j + 2);
            int c3 = __builtin_amdgcn_readlane(pk.x, j + 3);
            int c4 = __builtin_amdgcn_readlane(pk.x, j + 4);
            int c5 = __builtin_amdgcn_readlane(pk.x, j + 5);
            int c6 = __builtin_amdgcn_readlane(pk.x, j + 6);
            int c7 = __builtin_amdgcn_readlane(pk.x, j + 7);
            float x0 = bf2f(x[((long)c0 << 6) + lane]);
            float x1 = bf2f(x[((long)c1 << 6) + lane]);
            float x2 = bf2f(x[((long)c2 << 6) + lane]);
            float x3 = bf2f(x[((long)c3 << 6) + lane]);
            float x4 = bf2f(x[((long)c4 << 6) + lane]);
            float x5 = bf2f(x[((long)c5 << 6) + lane]);
            float x6 = bf2f(x[((long)c6 << 6) + lane]);
            float x7 = bf2f(x[((long)c7 << 6) + lane]);
            float v0 = __int_as_float(__builtin_amdgcn_readlane(pk.y, j + 0));
            float v1 = __int_as_float(__builtin_amdgcn_readlane(pk.y, j + 1));
            float v2 = __int_as_float(__builtin_amdgcn_readlane(pk.y, j + 2));
            float v3 = __int_as_float(__builtin_amdgcn_readlane(pk.y, j + 3));
            float v4 = __int_as_float(__builtin_amdgcn_readlane(pk.y, j + 4));
            float v5 = __int_as_float(__builtin_amdgcn_readlane(pk.y, j + 5));
            float v6 = __int_as_float(__builtin_amdgcn_readlane(pk.y, j + 6));
            float v7 = __int_as_float(__builtin_amdgcn_readlane(pk.y, j + 7));
            acc0 = fmaf(v0, x0, acc0);
            acc1 = fmaf(v1, x1, acc1);
            acc2 = fmaf(v2, x2, acc2);
            acc3 = fmaf(v3, x3, acc3);
            acc4 = fmaf(v4, x4, acc4);
            acc5 = fmaf(v5, x5, acc5);
            acc6 = fmaf(v6, x6, acc6);
            acc7 = fmaf(v7, x7, acc7);
        }
        for (; j < m; ++j) {
            int   c = __builtin_amdgcn_readlane(pk.x, j);
            float v = __int_as_float(__builtin_amdgcn_readlane(pk.y, j));
            acc0 = fmaf(v, bf2f(x[((long)c << 6) + lane]), acc0);
        }
    }
    float acc = ((acc0 + acc1) + (acc2 + acc3)) + ((acc4 + acc5) + (acc6 + acc7));

    long o = ((long)wid << 6) + lane;
    if (MODE == 0) {
        y[o] = f2bf(acc);
        out[o] += acc;
    } else {
        out[o] = (out[o] + acc) * 0.25f;
    }
}

// ------------------- fallback (round-1 atomic path, fp32) -------------------
__global__ void init_fp32_kernel(const float4* __restrict__ ue,
                                 const float4* __restrict__ ie,
                                 float4* __restrict__ cur,
                                 float4* __restrict__ out) {
    int i = blockIdx.x * blockDim.x + threadIdx.x;
    if (i >= N_TOT4) return;
    float4 v = (i < N_USER4) ? ue[i] : ie[i - N_USER4];
    cur[i] = v;
    out[i] = v;
}

__global__ void edge_kernel(const int*   __restrict__ row,
                            const int*   __restrict__ col,
                            const float* __restrict__ val,
                            const float* __restrict__ x,
                            float*       __restrict__ y) {
    long gid = (long)blockIdx.x * blockDim.x + threadIdx.x;
    int e = (int)(gid >> 4);
    if (e >= NUM_EDGES) return;
    int d = ((int)gid & 15) * 4;
    int   r = row[e];
    int   c = col[e];
    float v = val[e];
    const float4 xv = *(const float4*)(x + (long)c * EMBED_DIM + d);
    float* yp = y + (long)r * EMBED_DIM + d;
    atomicAdd(yp + 0, v * xv.x);
    atomicAdd(yp + 1, v * xv.y);
    atomicAdd(yp + 2, v * xv.z);
    atomicAdd(yp + 3, v * xv.w);
}

__global__ void update_kernel(float4* __restrict__ out,
                              const float4* __restrict__ nxt) {
    int i = blockIdx.x * blockDim.x + threadIdx.x;
    if (i >= N_TOT4) return;
    float4 o = out[i], n = nxt[i];
    o.x += n.x; o.y += n.y; o.z += n.z; o.w += n.w;
    out[i] = o;
}

__global__ void final_kernel(float4* __restrict__ out,
                             const float4* __restrict__ nxt) {
    int i = blockIdx.x * blockDim.x + threadIdx.x;
    if (i >= N_TOT4) return;
    float4 o = out[i], n = nxt[i];
    out[i] = make_float4((o.x + n.x) * 0.25f, (o.y + n.y) * 0.25f,
                         (o.z + n.z) * 0.25f, (o.w + n.w) * 0.25f);
}

__global__ void zero_buf_kernel(float4* __restrict__ b) {
    int i = blockIdx.x * blockDim.x + threadIdx.x;
    if (i < N_TOT4) b[i] = make_float4(0.f, 0.f, 0.f, 0.f);
}

extern "C" void kernel_launch(void* const* d_in, const int* in_sizes, int n_in,
                              void* d_out, int out_size, void* d_ws, size_t ws_size,
                              hipStream_t stream) {
    const float* user_emb  = (const float*)d_in[0];
    const float* item_emb  = (const float*)d_in[1];
    const float* edge_vals = (const float*)d_in[2];
    const int*   edge_row  = (const int*)  d_in[3];
    const int*   edge_col  = (const int*)  d_in[4];
    float* out = (float*)d_out;

    const int blk = 256;
    const int grid_nodes = (N_TOT4 + blk - 1) / blk;          // 9375
    const int grid_spmm  = (N_NODES * 64 + blk - 1) / blk;    // 37500

    const size_t BF     = (size_t)N_NODES * EMBED_DIM * sizeof(unsigned short); // 19.2 MB
    const size_t TMP    = (size_t)NB * CAP * sizeof(int2);    // 38.4 MB (overlays bfB)
    const size_t PACKED = (size_t)NUM_EDGES * sizeof(int2);   // 32 MB
    const size_t CNT    = (size_t)NTILES * NB * sizeof(int);  // 2.3 MB
    const size_t RP     = 600064;                             // (N_NODES+1)*4 padded
    // layout: bfA | tmp (bfB aliases its first 19.2 MB) | packed | cnt | rp | tot | boff
    const size_t need = BF + TMP + PACKED + CNT + RP + 8192;  // ~92.6 MB

    if (ws_size >= need) {
        unsigned short* bfA = (unsigned short*)d_ws;
        unsigned short* bfB = (unsigned short*)((char*)d_ws + BF);  // aliases tmp head
        int2* tmp     = (int2*)((char*)d_ws + BF);                  // dead before spmm L1
        int2* packed  = (int2*)((char*)d_ws + BF + TMP);
        int*  cnt     = (int*) ((char*)d_ws + BF + TMP + PACKED);
        int*  row_ptr = (int*) ((char*)d_ws + BF + TMP + PACKED + CNT);
        int*  tot     = (int*) ((char*)d_ws + BF + TMP + PACKED + CNT + RP);
        int*  boff    = tot + 1024;

        init_kernel<<<grid_nodes, blk, 0, stream>>>(
            (const float4*)user_emb, (const float4*)item_emb,
            (ushort4*)bfA, (float4*)out);

        // --- build CSR: counts -> column scan -> staged bin -> finalize ---
        bin_count<<<NTILES, blk, 0, stream>>>(edge_row, cnt);
        col_scan<<<NB, blk, 0, stream>>>(cnt, tot);
        boff_scan<<<1, 1024, 0, stream>>>(tot, boff);
        bin_write<<<NTILES, blk, 0, stream>>>(edge_row, edge_col, edge_vals,
                                              cnt, tmp);
        finalize_bucket<<<NB, blk, 0, stream>>>(tmp, tot, boff, row_ptr, packed);

        // --- 3 propagation layers (spmm L1's bfB write clobbers dead tmp) ---
        spmm_kernel<0><<<grid_spmm, blk, 0, stream>>>(row_ptr, packed, bfA, bfB, out);
        spmm_kernel<0><<<grid_spmm, blk, 0, stream>>>(row_ptr, packed, bfB, bfA, out);
        spmm_kernel<1><<<grid_spmm, blk, 0, stream>>>(row_ptr, packed, bfA, bfB, out);
    } else {
        // fallback: round-1 atomic scatter path (fp32, needs 76.8 MB)
        const size_t BUF = (size_t)N_NODES * EMBED_DIM * sizeof(float);
        float* bufA = (float*)d_ws;
        float* bufB = (float*)((char*)d_ws + BUF);
        const long edge_threads = (long)NUM_EDGES * 16;
        const int grid_edges16 = (int)((edge_threads + blk - 1) / blk);

        init_fp32_kernel<<<grid_nodes, blk, 0, stream>>>(
            (const float4*)user_emb, (const float4*)item_emb,
            (float4*)bufA, (float4*)out);
        zero_buf_kernel<<<grid_nodes, blk, 0, stream>>>((float4*)bufB);

        edge_kernel<<<grid_edges16, blk, 0, stream>>>(edge_row, edge_col, edge_vals, bufA, bufB);
        update_kernel<<<grid_nodes, blk, 0, stream>>>((float4*)out, (const float4*)bufB);
        zero_buf_kernel<<<grid_nodes, blk, 0, stream>>>((float4*)bufA);

        edge_kernel<<<grid_edges16, blk, 0, stream>>>(edge_row, edge_col, edge_vals, bufB, bufA);
        update_kernel<<<grid_nodes, blk, 0, stream>>>((float4*)out, (const float4*)bufA);
        zero_buf_kernel<<<grid_nodes, blk, 0, stream>>>((float4*)bufB);

        edge_kernel<<<grid_edges16, blk, 0, stream>>>(edge_row, edge_col, edge_vals, bufA, bufB);
        final_kernel<<<grid_nodes, blk, 0, stream>>>((float4*)out, (const float4*)bufB);
    }
}